// Round 22
// baseline (120.938 us; speedup 1.0000x reference)
//
#include <hip/hip_runtime.h>
#include <stdint.h>

// Problem constants
#define BB 2
#define SS 2048
#define DD 1024
#define HH 16
#define DK 64

// 0.125 (1/sqrt(DK)) * log2(e): QK^T scores land in log2 domain -> exp2 softmax
#define QSCALE 0.1803368801111204f
// finite mask sentinel
#define NEGS -1.0e30f

typedef short s16x8 __attribute__((ext_vector_type(8)));
typedef float f32x4 __attribute__((ext_vector_type(4)));
typedef unsigned short u16x4 __attribute__((ext_vector_type(4)));
typedef unsigned int u32x4 __attribute__((ext_vector_type(4)));

static __device__ __forceinline__ unsigned short f2bf(float f) {
  unsigned int u = __builtin_bit_cast(unsigned int, f);
  u = (u + 0x7fffu + ((u >> 16) & 1u)) >> 16;
  return (unsigned short)u;
}

static __device__ __forceinline__ float bf2f(unsigned short s) {
  unsigned int u = ((unsigned int)s) << 16;
  return __builtin_bit_cast(float, u);
}

// v_cvt_pk_bf16_f32: lo -> low 16, hi -> high 16 (RTNE)
static __device__ __forceinline__ unsigned int cvtpk(float lo, float hi) {
  unsigned int r;
  asm("v_cvt_pk_bf16_f32 %0, %1, %2" : "=v"(r) : "v"(lo), "v"(hi));
  return r;
}

static __device__ __forceinline__ f32x4 mfma16(s16x8 a, s16x8 b, f32x4 c) {
  return __builtin_amdgcn_mfma_f32_16x16x32_bf16(a, b, c, 0, 0, 0);
}

static __device__ __forceinline__ void gload_lds16(const void* g, void* l) {
  __builtin_amdgcn_global_load_lds(
      (const __attribute__((address_space(1))) unsigned int*)g,
      (__attribute__((address_space(3))) unsigned int*)l, 16, 0, 0);
}

// ---------------- fp32 -> bf16 convert, all 3 tensors in one launch ----------------
__global__ __launch_bounds__(256) void cvt3_kernel(const float* __restrict__ q,
                                                   const float* __restrict__ k,
                                                   const float* __restrict__ v,
                                                   unsigned short* __restrict__ qb,
                                                   unsigned short* __restrict__ kb,
                                                   unsigned short* __restrict__ vb) {
  int sel = blockIdx.y;
  const float* in = (sel == 0) ? q : ((sel == 1) ? k : v);
  unsigned short* out = (sel == 0) ? qb : ((sel == 1) ? kb : vb);
  int i = blockIdx.x * 256 + threadIdx.x;
  f32x4 vv = ((const f32x4*)in)[i];
  u16x4 o;
  o.x = f2bf(vv.x); o.y = f2bf(vv.y); o.z = f2bf(vv.z); o.w = f2bf(vv.w);
  ((u16x4*)out)[i] = o;
}

// ---------------- all 4 W [K][N] fp32 -> WT [N][K] bf16 in one launch ----------------
__global__ __launch_bounds__(256) void transpose_w4_kernel(const float* __restrict__ Wq,
                                                           const float* __restrict__ Wk,
                                                           const float* __restrict__ Wv,
                                                           const float* __restrict__ Wo,
                                                           unsigned short* __restrict__ WTbase) {
  __shared__ float t[32][33];
  int z = blockIdx.z;
  const float* W = (z == 0) ? Wq : ((z == 1) ? Wk : ((z == 2) ? Wv : Wo));
  float scale = (z == 0) ? QSCALE : 1.0f;
  unsigned short* WT = WTbase + (size_t)z * DD * DD;
  int n0 = blockIdx.x * 32, k0 = blockIdx.y * 32;
  int tx = threadIdx.x, ty = threadIdx.y;
  for (int i = 0; i < 4; ++i)
    t[ty + 8 * i][tx] = W[(size_t)(k0 + ty + 8 * i) * DD + n0 + tx];
  __syncthreads();
  for (int i = 0; i < 4; ++i)
    WT[(size_t)(n0 + ty + 8 * i) * DD + k0 + tx] = f2bf(t[tx][ty + 8 * i] * scale);
}

// ---------------- fused QKV projection GEMM (128x64 tile, BK=64, dbuf) ----------------
// 1-D grid 1536, XCD-bijective (r13 FETCH win). BK=64 halves barrier/drain
// events (r18-proven). Q,K write [B*H][S][DK]; V writes TRANSPOSED [B*H][DK][S].
__global__ __launch_bounds__(256) void gemm_qkv_kernel(
    const unsigned short* __restrict__ qb, const unsigned short* __restrict__ kb,
    const unsigned short* __restrict__ vb, const unsigned short* __restrict__ WTbase,
    const float* __restrict__ bq, const float* __restrict__ bk,
    const float* __restrict__ bv, unsigned short* __restrict__ Qh,
    unsigned short* __restrict__ Kh, unsigned short* __restrict__ VhT) {
  const int K = DD;
  __shared__ __align__(16) unsigned short Alds[2][128 * 64];  // 16KB/buf
  __shared__ __align__(16) unsigned short Blds[2][64 * 64];   // 8KB/buf
  int tid = threadIdx.x;
  int lane = tid & 63, wave = tid >> 6;
  int g = lane >> 4, r16 = lane & 15;

  int bid = blockIdx.x;
  int logical = (bid & 7) * 192 + (bid >> 3);  // bijective: 1536 = 8 XCDs x 192
  int y = logical >> 4, xn = logical & 15;     // y: seg*32 + m-tile, xn: n-tile
  int seg = y >> 5;
  int m0 = (y & 31) * 128, n0 = xn * 64;
  int wm = (wave >> 1) * 64, wn = (wave & 1) * 32;

  const unsigned short* A = (seg == 0) ? qb : ((seg == 1) ? kb : vb);
  const unsigned short* BT = WTbase + (size_t)seg * DD * DD;
  const float* bias = (seg == 0) ? bq : ((seg == 1) ? bk : bv);
  float bsc = (seg == 0) ? QSCALE : 1.0f;

  f32x4 acc[4][2] = {};

  int ar[4], ac[4];
#pragma unroll
  for (int i = 0; i < 4; ++i) {
    int c = tid + 256 * i;
    ar[i] = c >> 3;
    ac[i] = (c & 7) ^ (ar[i] & 7);
  }
  int br[2], bc[2];
#pragma unroll
  for (int i = 0; i < 2; ++i) {
    int c = tid + 256 * i;
    br[i] = c >> 3;
    bc[i] = (c & 7) ^ (br[i] & 7);
  }

#define STAGE_AB(buf, k0)                                                          \
  do {                                                                             \
    _Pragma("unroll") for (int i = 0; i < 4; ++i)                                  \
        gload_lds16((const char*)(A + (size_t)(m0 + ar[i]) * K + (k0)) + ac[i] * 16, \
                    (char*)Alds[buf] + wave * 1024 + i * 4096);                    \
    _Pragma("unroll") for (int i = 0; i < 2; ++i)                                  \
        gload_lds16((const char*)(BT + (size_t)(n0 + br[i]) * K + (k0)) + bc[i] * 16, \
                    (char*)Blds[buf] + wave * 1024 + i * 4096);                    \
  } while (0)

  STAGE_AB(0, 0);
  int cur = 0;

  for (int k0 = 0; k0 < K; k0 += 64) {
    __syncthreads();  // drains staging of buf[cur]; buf[cur^1] free to overwrite
    if (k0 + 64 < K) STAGE_AB(cur ^ 1, k0 + 64);

#pragma unroll
    for (int ks = 0; ks < 2; ++ks) {
      s16x8 af[4], bfr[2];
#pragma unroll
      for (int mt = 0; mt < 4; ++mt) {
        int row = wm + mt * 16 + r16;
        int ch = (ks * 4 + g) ^ (row & 7);
        af[mt] = *(const s16x8*)((const char*)Alds[cur] + row * 128 + ch * 16);
      }
#pragma unroll
      for (int nt = 0; nt < 2; ++nt) {
        int row = wn + nt * 16 + r16;
        int ch = (ks * 4 + g) ^ (row & 7);
        bfr[nt] = *(const s16x8*)((const char*)Blds[cur] + row * 128 + ch * 16);
      }
      __builtin_amdgcn_s_setprio(1);
#pragma unroll
      for (int mt = 0; mt < 4; ++mt)
#pragma unroll
        for (int nt = 0; nt < 2; ++nt)
          acc[mt][nt] = mfma16(af[mt], bfr[nt], acc[mt][nt]);
      __builtin_amdgcn_s_setprio(0);
    }
    cur ^= 1;
  }
#undef STAGE_AB

  unsigned short* outh = (seg == 0) ? Qh : Kh;
#pragma unroll
  for (int nt = 0; nt < 2; ++nt) {
    int col = n0 + wn + nt * 16 + r16;
    int h = col >> 6, dk = col & (DK - 1);
    float bvv = bias[col] * bsc;
#pragma unroll
    for (int mt = 0; mt < 4; ++mt) {
      int row0g = m0 + wm + mt * 16 + g * 4;
      int bb = row0g >> 11, s0 = row0g & (SS - 1);
      if (seg == 2) {
        u16x4 o;
#pragma unroll
        for (int rr = 0; rr < 4; ++rr) o[rr] = f2bf(acc[mt][nt][rr] + bvv);
        *(u16x4*)&VhT[((size_t)(bb * HH + h) * DK + dk) * SS + s0] = o;
      } else {
#pragma unroll
        for (int rr = 0; rr < 4; ++rr) {
          outh[(((size_t)bb * HH + h) * SS + s0 + rr) * DK + dk] =
              f2bf(acc[mt][nt][rr] + bvv);
        }
      }
    }
  }
}

// ---------------- output GEMM (128x64 tile, dbuf, grid 512) ----------------
__global__ __launch_bounds__(256) void gemm_out_kernel(const unsigned short* __restrict__ A,
                                                       const unsigned short* __restrict__ BT,
                                                       const float* __restrict__ bias,
                                                       float* __restrict__ out) {
  const int K = DD;
  __shared__ __align__(16) unsigned short Alds[2][128 * 32];
  __shared__ __align__(16) unsigned short Blds[2][64 * 32];
  int tid = threadIdx.x;
  int lane = tid & 63, wave = tid >> 6;
  int g = lane >> 4, r16 = lane & 15;

  int bid = blockIdx.x;
  int logical = (bid & 7) * 64 + (bid >> 3);  // bijective: 512 = 8 XCDs x 64
  int m0 = (logical >> 4) * 128, n0 = (logical & 15) * 64;
  int wm = (wave >> 1) * 64, wn = (wave & 1) * 32;

  f32x4 acc[4][2] = {};

  int c0 = tid, c1 = tid + 256;
  int arow0 = c0 >> 2, arow1 = c1 >> 2;
  int as0 = (c0 & 3) ^ ((arow0 >> 1) & 3);
  int as1 = (c1 & 3) ^ ((arow1 >> 1) & 3);

#define STAGE_AB(buf, k0)                                                        \
  do {                                                                           \
    gload_lds16((const char*)(A + (size_t)(m0 + arow0) * K + (k0)) + as0 * 16,   \
                (char*)Alds[buf] + wave * 1024);                                 \
    gload_lds16((const char*)(A + (size_t)(m0 + arow1) * K + (k0)) + as1 * 16,   \
                (char*)Alds[buf] + wave * 1024 + 4096);                          \
    gload_lds16((const char*)(BT + (size_t)(n0 + arow0) * K + (k0)) + as0 * 16,  \
                (char*)Blds[buf] + wave * 1024);                                 \
  } while (0)

  STAGE_AB(0, 0);
  int cur = 0;

  for (int k0 = 0; k0 < K; k0 += 32) {
    __syncthreads();
    if (k0 + 32 < K) STAGE_AB(cur ^ 1, k0 + 32);

    s16x8 af[4], bfr[2];
#pragma unroll
    for (int mt = 0; mt < 4; ++mt) {
      int row = wm + mt * 16 + r16;
      int ch = g ^ ((row >> 1) & 3);
      af[mt] = *(const s16x8*)((const char*)Alds[cur] + row * 64 + ch * 16);
    }
#pragma unroll
    for (int nt = 0; nt < 2; ++nt) {
      int row = wn + nt * 16 + r16;
      int ch = g ^ ((row >> 1) & 3);
      bfr[nt] = *(const s16x8*)((const char*)Blds[cur] + row * 64 + ch * 16);
    }
    __builtin_amdgcn_s_setprio(1);
#pragma unroll
    for (int mt = 0; mt < 4; ++mt)
#pragma unroll
      for (int nt = 0; nt < 2; ++nt)
        acc[mt][nt] = mfma16(af[mt], bfr[nt], acc[mt][nt]);
    __builtin_amdgcn_s_setprio(0);
    cur ^= 1;
  }
#undef STAGE_AB

#pragma unroll
  for (int nt = 0; nt < 2; ++nt) {
    int col = n0 + wn + nt * 16 + r16;
    float bvv = bias[col];
#pragma unroll
    for (int mt = 0; mt < 4; ++mt) {
#pragma unroll
      for (int rr = 0; rr < 4; ++rr) {
        int rowg = m0 + wm + mt * 16 + g * 4 + rr;
        out[(size_t)rowg * DD + col] = acc[mt][nt][rr] + bvv;
      }
    }
  }
}

// ---------------- causal flash attention, dual-chain waves + split pairs ----------------
// r18/r20-proven configuration (T15 cross-tile PV reverted: r21 measured it
// slightly negative). Stage-1-ahead double-buffered KV staging, split-pair
// uniform blocks, dual independent softmax chains per wave.
__global__ __launch_bounds__(256) void attn_kernel(const unsigned short* __restrict__ Qh,
                                                   const unsigned short* __restrict__ Kh,
                                                   const unsigned short* __restrict__ VhT,
                                                   unsigned short* __restrict__ ctx,
                                                   unsigned short* __restrict__ Opart,
                                                   float2* __restrict__ mlpart) {
  __shared__ __align__(16) unsigned short Klds[2][64 * 64];  // [key][dk], swz (r&3)|(((r>>3)&1)<<2)
  __shared__ __align__(16) unsigned short Vlds[2][64 * 64];  // [d][key], swz r&7

  int tid = threadIdx.x;
  int lane = tid & 63, wave = tid >> 6;
  int g = lane >> 4, r16 = lane & 15;
  int bid = blockIdx.x;
  int x = bid >> 3;
  int pid = x & 7;
  int hf = (x >> 3) & 1;
  int bh = ((x >> 4) << 3) | (bid & 7);

  int tilesA = hf ? 0 : 2 * pid + 2;  // segA kv-tile count (h0 only)
  const int NT = 17;
  int q0A = pid * 128, q0B = (15 - pid) * 128;
  int kvoffB = hf ? (15 - 2 * pid) : 0;  // h1 segB starts at this kv-tile

  const unsigned short* Qb = Qh + (size_t)bh * SS * DK;
  const char* Kb = (const char*)(Kh + (size_t)bh * SS * DK);
  const char* Vb = (const char*)(VhT + (size_t)bh * DK * SS);

  // K-frag read constants: row(nt) = 8a + b + 4*(nt&1) + 32*(nt>>1); swizzle sk = b + 4*(a&1)
  int a_ = r16 >> 2, b_ = r16 & 3;
  int rbase = 8 * a_ + b_;
  int sk = b_ + 4 * (a_ & 1);

  // staging geometry; pre-swizzled source
  int c0 = tid, c1 = tid + 256;
  int row0 = c0 >> 3, row1 = c1 >> 3;
  int skst0 = ((row0 & 3) | (((row0 >> 3) & 1) << 2));
  int skst1 = ((row1 & 3) | (((row1 >> 3) & 1) << 2));
  int kc0 = (c0 & 7) ^ skst0, kc1 = (c1 & 7) ^ skst1;
  int vc0 = (c0 & 7) ^ (row0 & 7), vc1 = (c1 & 7) ^ (row1 & 7);

#define KV_OF(t) ((hf ? (kvoffB + (t)) : (((t) < tilesA) ? (t) : ((t) - tilesA))) * 64)
#define STAGE_KV(buf, kv0)                                                   \
  do {                                                                       \
    gload_lds16(Kb + ((size_t)((kv0) + row0) * 128) + kc0 * 16,              \
                (char*)Klds[buf] + wave * 1024);                             \
    gload_lds16(Kb + ((size_t)((kv0) + row1) * 128) + kc1 * 16,              \
                (char*)Klds[buf] + wave * 1024 + 4096);                      \
    gload_lds16(Vb + ((size_t)row0 * SS + (kv0)) * 2 + vc0 * 16,             \
                (char*)Vlds[buf] + wave * 1024);                             \
    gload_lds16(Vb + ((size_t)row1 * SS + (kv0)) * 2 + vc1 * 16,             \
                (char*)Vlds[buf] + wave * 1024 + 4096);                      \
  } while (0)

  int b = bh >> 4, h = bh & (HH - 1);

  // starting segment: A for h0, B for h1. Wave owns rows [qw0, qw0+32).
  int qw0 = (hf ? q0B : q0A) + wave * 32;
  s16x8 aq[2][2];
#pragma unroll
  for (int mt = 0; mt < 2; ++mt)
#pragma unroll
    for (int kc = 0; kc < 2; ++kc)
      aq[mt][kc] = *(const s16x8*)(Qb + (size_t)(qw0 + mt * 16 + r16) * DK + kc * 32 + g * 8);

  STAGE_KV(0, KV_OF(0));

  f32x4 accd[2][4] = {};  // [mt][dsub]: O^T[d=dsub*16+4g+rr][q=qw0+mt*16+r16]
  float mrow[2] = {-INFINITY, -INFINITY};
  float lrow[2] = {0.0f, 0.0f};

  for (int t = 0; t < NT; ++t) {
    if (hf == 0 && t == tilesA) {
      // segA complete: final write for q-tile pid (both chains); reset for segB
#pragma unroll
      for (int mt = 0; mt < 2; ++mt) {
        float inv = 1.0f / lrow[mt];
        int srow = qw0 + mt * 16 + r16;
#pragma unroll
        for (int dsub = 0; dsub < 4; ++dsub) {
          int d0 = dsub * 16 + 4 * g;
          u16x4 o;
#pragma unroll
          for (int rr = 0; rr < 4; ++rr) o[rr] = f2bf(accd[mt][dsub][rr] * inv);
          *(u16x4*)&ctx[(((size_t)b * SS + srow) * HH + h) * DK + d0] = o;
        }
      }
      qw0 = q0B + wave * 32;
#pragma unroll
      for (int mt = 0; mt < 2; ++mt)
#pragma unroll
        for (int kc = 0; kc < 2; ++kc)
          aq[mt][kc] = *(const s16x8*)(Qb + (size_t)(qw0 + mt * 16 + r16) * DK + kc * 32 + g * 8);
#pragma unroll
      for (int mt = 0; mt < 2; ++mt) {
#pragma unroll
        for (int dsub = 0; dsub < 4; ++dsub) accd[mt][dsub] = (f32x4){0.f, 0.f, 0.f, 0.f};
        mrow[mt] = -INFINITY;
        lrow[mt] = 0.0f;
      }
    }

    int kv0 = KV_OF(t);

    __syncthreads();  // fence + drain + barrier (proven r10 sync)
    if (t + 1 < NT) STAGE_KV((t + 1) & 1, KV_OF(t + 1));

    const char* Kc = (const char*)Klds[t & 1];
    const char* Vc = (const char*)Vlds[t & 1];

    // ---- QK^T (swapped), both chains share bk fragments
    f32x4 sf[2][4] = {};
    __builtin_amdgcn_s_setprio(1);
#pragma unroll
    for (int kc = 0; kc < 2; ++kc) {
      s16x8 bk[4];
#pragma unroll
      for (int nt = 0; nt < 4; ++nt) {
        int row = rbase + 4 * (nt & 1) + 32 * (nt >> 1);
        int ch = (kc * 4 + g) ^ sk;
        bk[nt] = *(const s16x8*)(Kc + row * 128 + ch * 16);
      }
#pragma unroll
      for (int nt = 0; nt < 4; ++nt) {
        sf[0][nt] = mfma16(bk[nt], aq[0][kc], sf[0][nt]);
        sf[1][nt] = mfma16(bk[nt], aq[1][kc], sf[1][nt]);
      }
    }
    __builtin_amdgcn_s_setprio(0);

    // ---- prefetch V fragments (shared by both chains)
    s16x8 av[2][4];
#pragma unroll
    for (int c = 0; c < 2; ++c)
#pragma unroll
      for (int dsub = 0; dsub < 4; ++dsub) {
        int row = dsub * 16 + r16;
        int ch = (c * 4 + g) ^ (row & 7);
        av[c][dsub] = *(const s16x8*)(Vc + row * 128 + ch * 16);
      }

    bool domask = (kv0 + 63 > qw0);
    unsigned int pk[2][2][4];
#pragma unroll
    for (int mt = 0; mt < 2; ++mt) {
      // ---- mask (diagonal tiles only); finite sentinel
      if (domask) {
        int thr = qw0 + mt * 16 + r16 - kv0 - 8 * g;
#pragma unroll
        for (int nt = 0; nt < 4; ++nt) {
          int koff = 4 * (nt & 1) + 32 * (nt >> 1);
#pragma unroll
          for (int rr = 0; rr < 4; ++rr)
            if (koff + rr > thr) sf[mt][nt][rr] = NEGS;
        }
      }

      // ---- online softmax (log2 domain), tree reductions (depth 4)
      float m0v = fmaxf(fmaxf(sf[mt][0][0], sf[mt][0][1]), fmaxf(sf[mt][0][2], sf[mt][0][3]));
      float m1v = fmaxf(fmaxf(sf[mt][1][0], sf[mt][1][1]), fmaxf(sf[mt][1][2], sf[mt][1][3]));
      float m2v = fmaxf(fmaxf(sf[mt][2][0], sf[mt][2][1]), fmaxf(sf[mt][2][2], sf[mt][2][3]));
      float m3v = fmaxf(fmaxf(sf[mt][3][0], sf[mt][3][1]), fmaxf(sf[mt][3][2], sf[mt][3][3]));
      float tmax = fmaxf(fmaxf(m0v, m1v), fmaxf(m2v, m3v));
      tmax = fmaxf(tmax, __shfl_xor(tmax, 16));
      tmax = fmaxf(tmax, __shfl_xor(tmax, 32));

      if (!__all(tmax <= mrow[mt])) {  // exact defer
        float mn = fmaxf(mrow[mt], tmax);
        float fc = __builtin_amdgcn_exp2f(mrow[mt] - mn);
        lrow[mt] *= fc;
        mrow[mt] = mn;
#pragma unroll
        for (int dsub = 0; dsub < 4; ++dsub)
#pragma unroll
          for (int rr = 0; rr < 4; ++rr) accd[mt][dsub][rr] *= fc;
      }

      float pf[4][4];
#pragma unroll
      for (int nt = 0; nt < 4; ++nt)
#pragma unroll
        for (int rr = 0; rr < 4; ++rr)
          pf[nt][rr] = __builtin_amdgcn_exp2f(sf[mt][nt][rr] - mrow[mt]);
      float s0v = (pf[0][0] + pf[0][1]) + (pf[0][2] + pf[0][3]);
      float s1v = (pf[1][0] + pf[1][1]) + (pf[1][2] + pf[1][3]);
      float s2v = (pf[2][0] + pf[2][1]) + (pf[2][2] + pf[2][3]);
      float s3v = (pf[3][0] + pf[3][1]) + (pf[3][2] + pf[3][3]);
      float su = (s0v + s1v) + (s2v + s3v);
      su += __shfl_xor(su, 16);
      su += __shfl_xor(su, 32);
      lrow[mt] += su;

      // pack P^T fragments
#pragma unroll
      for (int c = 0; c < 2; ++c) {
        pk[mt][c][0] = cvtpk(pf[2 * c][0], pf[2 * c][1]);
        pk[mt][c][1] = cvtpk(pf[2 * c][2], pf[2 * c][3]);
        pk[mt][c][2] = cvtpk(pf[2 * c + 1][0], pf[2 * c + 1][1]);
        pk[mt][c][3] = cvtpk(pf[2 * c + 1][2], pf[2 * c + 1][3]);
      }
    }

    // ---- PV (swapped), av shared by both chains
    __builtin_amdgcn_s_setprio(1);
#pragma unroll
    for (int c = 0; c < 2; ++c) {
      s16x8 pb0 = __builtin_bit_cast(s16x8, *(u32x4*)pk[0][c]);
      s16x8 pb1 = __builtin_bit_cast(s16x8, *(u32x4*)pk[1][c]);
#pragma unroll
      for (int dsub = 0; dsub < 4; ++dsub) {
        accd[0][dsub] = mfma16(av[c][dsub], pb0, accd[0][dsub]);
        accd[1][dsub] = mfma16(av[c][dsub], pb1, accd[1][dsub]);
      }
    }
    __builtin_amdgcn_s_setprio(0);
  }

  // epilogue: write segB partial (slot = bh*8+pid, half hf), 128 rows/slot
#pragma unroll
  for (int mt = 0; mt < 2; ++mt) {
    size_t prow = ((size_t)bh * 8 + pid) * 128 + wave * 32 + mt * 16 + r16;
    float inv = 1.0f / lrow[mt];
    unsigned short* Op = Opart + ((size_t)hf * 32768 + prow) * 64;
#pragma unroll
    for (int dsub = 0; dsub < 4; ++dsub) {
      int d0 = dsub * 16 + 4 * g;
      u16x4 o;
#pragma unroll
      for (int rr = 0; rr < 4; ++rr) o[rr] = f2bf(accd[mt][dsub][rr] * inv);
      *(u16x4*)&Op[d0] = o;
    }
    if (g == 0) mlpart[(size_t)hf * 32768 + prow] = make_float2(mrow[mt], lrow[mt]);
  }
#undef STAGE_KV
#undef KV_OF
}

// ---------------- combine 2 partials per segB q-row ----------------
__global__ __launch_bounds__(256) void combine_kernel(const unsigned short* __restrict__ Opart,
                                                      const float2* __restrict__ mlpart,
                                                      unsigned short* __restrict__ ctx) {
  int idx = blockIdx.x * 256 + threadIdx.x;
  int row = idx >> 4;          // 32768 rows = 256 slots x 128 rows
  int d0 = (idx & 15) * 4;
  float2 ml0 = mlpart[row];
  float2 ml1 = mlpart[32768 + row];
  float m = fmaxf(ml0.x, ml1.x);
  float w0 = __builtin_amdgcn_exp2f(ml0.x - m) * ml0.y;
  float w1 = __builtin_amdgcn_exp2f(ml1.x - m) * ml1.y;
  float inv = 1.0f / (w0 + w1);
  w0 *= inv;
  w1 *= inv;
  u16x4 a = *(const u16x4*)(Opart + (size_t)row * 64 + d0);
  u16x4 bb4 = *(const u16x4*)(Opart + ((size_t)32768 + row) * 64 + d0);
  u16x4 o;
#pragma unroll
  for (int j = 0; j < 4; ++j) o[j] = f2bf(bf2f(a[j]) * w0 + bf2f(bb4[j]) * w1);
  int p = row >> 7, rin = row & 127;
  int bh = p >> 3, pid = p & 7;
  int srow = (15 - pid) * 128 + rin;
  int b = bh >> 4, h = bh & (HH - 1);
  *(u16x4*)&ctx[(((size_t)b * SS + srow) * HH + h) * DK + d0] = o;
}

extern "C" void kernel_launch(void* const* d_in, const int* in_sizes, int n_in,
                              void* d_out, int out_size, void* d_ws, size_t ws_size,
                              hipStream_t stream) {
  const float* q = (const float*)d_in[0];
  const float* k = (const float*)d_in[1];
  const float* v = (const float*)d_in[2];
  // d_in[3] = mask: exact causal tril, implemented in-kernel
  const float* Wq = (const float*)d_in[4];
  const float* bq = (const float*)d_in[5];
  const float* Wk = (const float*)d_in[6];
  const float* bk = (const float*)d_in[7];
  const float* Wv = (const float*)d_in[8];
  const float* bv = (const float*)d_in[9];
  const float* Wo = (const float*)d_in[10];
  const float* bo = (const float*)d_in[11];

  // Workspace layout (56 MB):
  //   [ 0, 8)  qb  -> reused as ctx
  //   [ 8,16)  kb  -> reused as Opart (2 x 4MB, dead after gemm_qkv)
  //   [16,24)  vb
  //   [24,32)  WT[4]; WqT region [24,26) -> reused as mlpart (512KB, dead after gemm_qkv)
  //   [32,40) Qh   [40,48) Kh   [48,56) VhT (written transposed by gemm_qkv)
  char* ws = (char*)d_ws;
  const size_t MB = 1ull << 20;
  unsigned short* qb = (unsigned short*)(ws + 0 * MB);
  unsigned short* kb = (unsigned short*)(ws + 8 * MB);
  unsigned short* vb = (unsigned short*)(ws + 16 * MB);
  unsigned short* WTbase = (unsigned short*)(ws + 24 * MB);
  unsigned short* WoT = (unsigned short*)(ws + 30 * MB);
  unsigned short* Qh = (unsigned short*)(ws + 32 * MB);
  unsigned short* Kh = (unsigned short*)(ws + 40 * MB);
  unsigned short* VhT = (unsigned short*)(ws + 48 * MB);
  unsigned short* ctx = (unsigned short*)(ws + 0 * MB);    // reuse qb
  unsigned short* Opart = (unsigned short*)(ws + 8 * MB);  // reuse kb (8MB)
  float2* mlpart = (float2*)(ws + 24 * MB);                // reuse WqT (512KB)

  const int n4 = BB * SS * DD / 4;

  cvt3_kernel<<<dim3(n4 / 256, 3), 256, 0, stream>>>(q, k, v, qb, kb, vb);

  dim3 tb(32, 8);
  transpose_w4_kernel<<<dim3(32, 32, 4), tb, 0, stream>>>(Wq, Wk, Wv, Wo, WTbase);

  gemm_qkv_kernel<<<1536, 256, 0, stream>>>(qb, kb, vb, WTbase,
                                            bq, bk, bv, Qh, Kh, VhT);

  attn_kernel<<<512, 256, 0, stream>>>(Qh, Kh, VhT, ctx, Opart, mlpart);

  combine_kernel<<<2048, 256, 0, stream>>>(Opart, mlpart, ctx);

  gemm_out_kernel<<<512, 256, 0, stream>>>(ctx, WoT, bo, (float*)d_out);
}

// Round 23
// 118.586 us; speedup vs baseline: 1.0198x; 1.0198x over previous
//
#include <hip/hip_runtime.h>
#include <stdint.h>

// Problem constants
#define BB 2
#define SS 2048
#define DD 1024
#define HH 16
#define DK 64

// 0.125 (1/sqrt(DK)) * log2(e): QK^T scores land in log2 domain -> exp2 softmax
#define QSCALE 0.1803368801111204f
// finite mask sentinel
#define NEGS -1.0e30f

typedef short s16x8 __attribute__((ext_vector_type(8)));
typedef float f32x4 __attribute__((ext_vector_type(4)));
typedef unsigned short u16x4 __attribute__((ext_vector_type(4)));
typedef unsigned int u32x4 __attribute__((ext_vector_type(4)));

static __device__ __forceinline__ unsigned short f2bf(float f) {
  unsigned int u = __builtin_bit_cast(unsigned int, f);
  u = (u + 0x7fffu + ((u >> 16) & 1u)) >> 16;
  return (unsigned short)u;
}

static __device__ __forceinline__ float bf2f(unsigned short s) {
  unsigned int u = ((unsigned int)s) << 16;
  return __builtin_bit_cast(float, u);
}

// v_cvt_pk_bf16_f32: lo -> low 16, hi -> high 16 (RTNE)
static __device__ __forceinline__ unsigned int cvtpk(float lo, float hi) {
  unsigned int r;
  asm("v_cvt_pk_bf16_f32 %0, %1, %2" : "=v"(r) : "v"(lo), "v"(hi));
  return r;
}

static __device__ __forceinline__ f32x4 mfma16(s16x8 a, s16x8 b, f32x4 c) {
  return __builtin_amdgcn_mfma_f32_16x16x32_bf16(a, b, c, 0, 0, 0);
}

static __device__ __forceinline__ void gload_lds16(const void* g, void* l) {
  __builtin_amdgcn_global_load_lds(
      (const __attribute__((address_space(1))) unsigned int*)g,
      (__attribute__((address_space(3))) unsigned int*)l, 16, 0, 0);
}

// ---------------- fused prologue: cvt3 (blocks 0..12287) + transpose_w4 (12288..16383) ----
// cvt and W-transpose are mutually independent (disjoint I/O, both feed only
// gemm_qkv); fusing removes one launch boundary and overlaps the small
// transpose with cvt's tail. Branch is block-uniform -> __syncthreads safe.
__global__ __launch_bounds__(256) void prologue_kernel(
    const float* __restrict__ q, const float* __restrict__ k,
    const float* __restrict__ v, unsigned short* __restrict__ qb,
    unsigned short* __restrict__ kb, unsigned short* __restrict__ vb,
    const float* __restrict__ Wq, const float* __restrict__ Wk,
    const float* __restrict__ Wv, const float* __restrict__ Wo,
    unsigned short* __restrict__ WTbase) {
  __shared__ float t[32][33];
  int bid = blockIdx.x;
  int tid = threadIdx.x;
  if (bid < 12288) {
    // ---- fp32 -> bf16 convert (4096 blocks per tensor)
    int sel = bid >> 12;
    const float* in = (sel == 0) ? q : ((sel == 1) ? k : v);
    unsigned short* out = (sel == 0) ? qb : ((sel == 1) ? kb : vb);
    int i = (bid & 4095) * 256 + tid;
    f32x4 vv = ((const f32x4*)in)[i];
    u16x4 o;
    o.x = f2bf(vv.x); o.y = f2bf(vv.y); o.z = f2bf(vv.z); o.w = f2bf(vv.w);
    ((u16x4*)out)[i] = o;
  } else {
    // ---- W [K][N] fp32 -> WT [N][K] bf16 (1024 blocks per matrix)
    int tw = bid - 12288;
    int z = tw >> 10;
    int rem = tw & 1023;
    const float* W = (z == 0) ? Wq : ((z == 1) ? Wk : ((z == 2) ? Wv : Wo));
    float scale = (z == 0) ? QSCALE : 1.0f;
    unsigned short* WT = WTbase + (size_t)z * DD * DD;
    int n0 = (rem & 31) * 32, k0 = (rem >> 5) * 32;
    int tx = tid & 31, ty = tid >> 5;
    for (int i = 0; i < 4; ++i)
      t[ty + 8 * i][tx] = W[(size_t)(k0 + ty + 8 * i) * DD + n0 + tx];
    __syncthreads();
    for (int i = 0; i < 4; ++i)
      WT[(size_t)(n0 + ty + 8 * i) * DD + k0 + tx] = f2bf(t[tx][ty + 8 * i] * scale);
  }
}

// ---------------- fused QKV projection GEMM (128x64 tile, BK=64, dbuf) ----------------
// 1-D grid 1536, XCD-bijective (r13 FETCH win). BK=64 halves barrier/drain
// events (r18-proven). Q,K write [B*H][S][DK]; V writes TRANSPOSED [B*H][DK][S].
__global__ __launch_bounds__(256) void gemm_qkv_kernel(
    const unsigned short* __restrict__ qb, const unsigned short* __restrict__ kb,
    const unsigned short* __restrict__ vb, const unsigned short* __restrict__ WTbase,
    const float* __restrict__ bq, const float* __restrict__ bk,
    const float* __restrict__ bv, unsigned short* __restrict__ Qh,
    unsigned short* __restrict__ Kh, unsigned short* __restrict__ VhT) {
  const int K = DD;
  __shared__ __align__(16) unsigned short Alds[2][128 * 64];  // 16KB/buf
  __shared__ __align__(16) unsigned short Blds[2][64 * 64];   // 8KB/buf
  int tid = threadIdx.x;
  int lane = tid & 63, wave = tid >> 6;
  int g = lane >> 4, r16 = lane & 15;

  int bid = blockIdx.x;
  int logical = (bid & 7) * 192 + (bid >> 3);  // bijective: 1536 = 8 XCDs x 192
  int y = logical >> 4, xn = logical & 15;     // y: seg*32 + m-tile, xn: n-tile
  int seg = y >> 5;
  int m0 = (y & 31) * 128, n0 = xn * 64;
  int wm = (wave >> 1) * 64, wn = (wave & 1) * 32;

  const unsigned short* A = (seg == 0) ? qb : ((seg == 1) ? kb : vb);
  const unsigned short* BT = WTbase + (size_t)seg * DD * DD;
  const float* bias = (seg == 0) ? bq : ((seg == 1) ? bk : bv);
  float bsc = (seg == 0) ? QSCALE : 1.0f;

  f32x4 acc[4][2] = {};

  int ar[4], ac[4];
#pragma unroll
  for (int i = 0; i < 4; ++i) {
    int c = tid + 256 * i;
    ar[i] = c >> 3;
    ac[i] = (c & 7) ^ (ar[i] & 7);
  }
  int br[2], bc[2];
#pragma unroll
  for (int i = 0; i < 2; ++i) {
    int c = tid + 256 * i;
    br[i] = c >> 3;
    bc[i] = (c & 7) ^ (br[i] & 7);
  }

#define STAGE_AB(buf, k0)                                                          \
  do {                                                                             \
    _Pragma("unroll") for (int i = 0; i < 4; ++i)                                  \
        gload_lds16((const char*)(A + (size_t)(m0 + ar[i]) * K + (k0)) + ac[i] * 16, \
                    (char*)Alds[buf] + wave * 1024 + i * 4096);                    \
    _Pragma("unroll") for (int i = 0; i < 2; ++i)                                  \
        gload_lds16((const char*)(BT + (size_t)(n0 + br[i]) * K + (k0)) + bc[i] * 16, \
                    (char*)Blds[buf] + wave * 1024 + i * 4096);                    \
  } while (0)

  STAGE_AB(0, 0);
  int cur = 0;

  for (int k0 = 0; k0 < K; k0 += 64) {
    __syncthreads();  // drains staging of buf[cur]; buf[cur^1] free to overwrite
    if (k0 + 64 < K) STAGE_AB(cur ^ 1, k0 + 64);

#pragma unroll
    for (int ks = 0; ks < 2; ++ks) {
      s16x8 af[4], bfr[2];
#pragma unroll
      for (int mt = 0; mt < 4; ++mt) {
        int row = wm + mt * 16 + r16;
        int ch = (ks * 4 + g) ^ (row & 7);
        af[mt] = *(const s16x8*)((const char*)Alds[cur] + row * 128 + ch * 16);
      }
#pragma unroll
      for (int nt = 0; nt < 2; ++nt) {
        int row = wn + nt * 16 + r16;
        int ch = (ks * 4 + g) ^ (row & 7);
        bfr[nt] = *(const s16x8*)((const char*)Blds[cur] + row * 128 + ch * 16);
      }
      __builtin_amdgcn_s_setprio(1);
#pragma unroll
      for (int mt = 0; mt < 4; ++mt)
#pragma unroll
        for (int nt = 0; nt < 2; ++nt)
          acc[mt][nt] = mfma16(af[mt], bfr[nt], acc[mt][nt]);
      __builtin_amdgcn_s_setprio(0);
    }
    cur ^= 1;
  }
#undef STAGE_AB

  unsigned short* outh = (seg == 0) ? Qh : Kh;
#pragma unroll
  for (int nt = 0; nt < 2; ++nt) {
    int col = n0 + wn + nt * 16 + r16;
    int h = col >> 6, dk = col & (DK - 1);
    float bvv = bias[col] * bsc;
#pragma unroll
    for (int mt = 0; mt < 4; ++mt) {
      int row0g = m0 + wm + mt * 16 + g * 4;
      int bb = row0g >> 11, s0 = row0g & (SS - 1);
      if (seg == 2) {
        u16x4 o;
#pragma unroll
        for (int rr = 0; rr < 4; ++rr) o[rr] = f2bf(acc[mt][nt][rr] + bvv);
        *(u16x4*)&VhT[((size_t)(bb * HH + h) * DK + dk) * SS + s0] = o;
      } else {
#pragma unroll
        for (int rr = 0; rr < 4; ++rr) {
          outh[(((size_t)bb * HH + h) * SS + s0 + rr) * DK + dk] =
              f2bf(acc[mt][nt][rr] + bvv);
        }
      }
    }
  }
}

// ---------------- output GEMM (128x64 tile, dbuf, grid 512) ----------------
__global__ __launch_bounds__(256) void gemm_out_kernel(const unsigned short* __restrict__ A,
                                                       const unsigned short* __restrict__ BT,
                                                       const float* __restrict__ bias,
                                                       float* __restrict__ out) {
  const int K = DD;
  __shared__ __align__(16) unsigned short Alds[2][128 * 32];
  __shared__ __align__(16) unsigned short Blds[2][64 * 32];
  int tid = threadIdx.x;
  int lane = tid & 63, wave = tid >> 6;
  int g = lane >> 4, r16 = lane & 15;

  int bid = blockIdx.x;
  int logical = (bid & 7) * 64 + (bid >> 3);  // bijective: 512 = 8 XCDs x 64
  int m0 = (logical >> 4) * 128, n0 = (logical & 15) * 64;
  int wm = (wave >> 1) * 64, wn = (wave & 1) * 32;

  f32x4 acc[4][2] = {};

  int c0 = tid, c1 = tid + 256;
  int arow0 = c0 >> 2, arow1 = c1 >> 2;
  int as0 = (c0 & 3) ^ ((arow0 >> 1) & 3);
  int as1 = (c1 & 3) ^ ((arow1 >> 1) & 3);

#define STAGE_AB(buf, k0)                                                        \
  do {                                                                           \
    gload_lds16((const char*)(A + (size_t)(m0 + arow0) * K + (k0)) + as0 * 16,   \
                (char*)Alds[buf] + wave * 1024);                                 \
    gload_lds16((const char*)(A + (size_t)(m0 + arow1) * K + (k0)) + as1 * 16,   \
                (char*)Alds[buf] + wave * 1024 + 4096);                          \
    gload_lds16((const char*)(BT + (size_t)(n0 + arow0) * K + (k0)) + as0 * 16,  \
                (char*)Blds[buf] + wave * 1024);                                 \
  } while (0)

  STAGE_AB(0, 0);
  int cur = 0;

  for (int k0 = 0; k0 < K; k0 += 32) {
    __syncthreads();
    if (k0 + 32 < K) STAGE_AB(cur ^ 1, k0 + 32);

    s16x8 af[4], bfr[2];
#pragma unroll
    for (int mt = 0; mt < 4; ++mt) {
      int row = wm + mt * 16 + r16;
      int ch = g ^ ((row >> 1) & 3);
      af[mt] = *(const s16x8*)((const char*)Alds[cur] + row * 64 + ch * 16);
    }
#pragma unroll
    for (int nt = 0; nt < 2; ++nt) {
      int row = wn + nt * 16 + r16;
      int ch = g ^ ((row >> 1) & 3);
      bfr[nt] = *(const s16x8*)((const char*)Blds[cur] + row * 64 + ch * 16);
    }
    __builtin_amdgcn_s_setprio(1);
#pragma unroll
    for (int mt = 0; mt < 4; ++mt)
#pragma unroll
      for (int nt = 0; nt < 2; ++nt)
        acc[mt][nt] = mfma16(af[mt], bfr[nt], acc[mt][nt]);
    __builtin_amdgcn_s_setprio(0);
    cur ^= 1;
  }
#undef STAGE_AB

#pragma unroll
  for (int nt = 0; nt < 2; ++nt) {
    int col = n0 + wn + nt * 16 + r16;
    float bvv = bias[col];
#pragma unroll
    for (int mt = 0; mt < 4; ++mt) {
#pragma unroll
      for (int rr = 0; rr < 4; ++rr) {
        int rowg = m0 + wm + mt * 16 + g * 4 + rr;
        out[(size_t)rowg * DD + col] = acc[mt][nt][rr] + bvv;
      }
    }
  }
}

// ---------------- causal flash attention, dual-chain waves + split pairs ----------------
// r18/r20-proven configuration. Stage-1-ahead double-buffered KV staging,
// split-pair uniform blocks, dual independent softmax chains per wave.
__global__ __launch_bounds__(256) void attn_kernel(const unsigned short* __restrict__ Qh,
                                                   const unsigned short* __restrict__ Kh,
                                                   const unsigned short* __restrict__ VhT,
                                                   unsigned short* __restrict__ ctx,
                                                   unsigned short* __restrict__ Opart,
                                                   float2* __restrict__ mlpart) {
  __shared__ __align__(16) unsigned short Klds[2][64 * 64];  // [key][dk], swz (r&3)|(((r>>3)&1)<<2)
  __shared__ __align__(16) unsigned short Vlds[2][64 * 64];  // [d][key], swz r&7

  int tid = threadIdx.x;
  int lane = tid & 63, wave = tid >> 6;
  int g = lane >> 4, r16 = lane & 15;
  int bid = blockIdx.x;
  int x = bid >> 3;
  int pid = x & 7;
  int hf = (x >> 3) & 1;
  int bh = ((x >> 4) << 3) | (bid & 7);

  int tilesA = hf ? 0 : 2 * pid + 2;  // segA kv-tile count (h0 only)
  const int NT = 17;
  int q0A = pid * 128, q0B = (15 - pid) * 128;
  int kvoffB = hf ? (15 - 2 * pid) : 0;  // h1 segB starts at this kv-tile

  const unsigned short* Qb = Qh + (size_t)bh * SS * DK;
  const char* Kb = (const char*)(Kh + (size_t)bh * SS * DK);
  const char* Vb = (const char*)(VhT + (size_t)bh * DK * SS);

  // K-frag read constants: row(nt) = 8a + b + 4*(nt&1) + 32*(nt>>1); swizzle sk = b + 4*(a&1)
  int a_ = r16 >> 2, b_ = r16 & 3;
  int rbase = 8 * a_ + b_;
  int sk = b_ + 4 * (a_ & 1);

  // staging geometry; pre-swizzled source
  int c0 = tid, c1 = tid + 256;
  int row0 = c0 >> 3, row1 = c1 >> 3;
  int skst0 = ((row0 & 3) | (((row0 >> 3) & 1) << 2));
  int skst1 = ((row1 & 3) | (((row1 >> 3) & 1) << 2));
  int kc0 = (c0 & 7) ^ skst0, kc1 = (c1 & 7) ^ skst1;
  int vc0 = (c0 & 7) ^ (row0 & 7), vc1 = (c1 & 7) ^ (row1 & 7);

#define KV_OF(t) ((hf ? (kvoffB + (t)) : (((t) < tilesA) ? (t) : ((t) - tilesA))) * 64)
#define STAGE_KV(buf, kv0)                                                   \
  do {                                                                       \
    gload_lds16(Kb + ((size_t)((kv0) + row0) * 128) + kc0 * 16,              \
                (char*)Klds[buf] + wave * 1024);                             \
    gload_lds16(Kb + ((size_t)((kv0) + row1) * 128) + kc1 * 16,              \
                (char*)Klds[buf] + wave * 1024 + 4096);                      \
    gload_lds16(Vb + ((size_t)row0 * SS + (kv0)) * 2 + vc0 * 16,             \
                (char*)Vlds[buf] + wave * 1024);                             \
    gload_lds16(Vb + ((size_t)row1 * SS + (kv0)) * 2 + vc1 * 16,             \
                (char*)Vlds[buf] + wave * 1024 + 4096);                      \
  } while (0)

  int b = bh >> 4, h = bh & (HH - 1);

  // starting segment: A for h0, B for h1. Wave owns rows [qw0, qw0+32).
  int qw0 = (hf ? q0B : q0A) + wave * 32;
  s16x8 aq[2][2];
#pragma unroll
  for (int mt = 0; mt < 2; ++mt)
#pragma unroll
    for (int kc = 0; kc < 2; ++kc)
      aq[mt][kc] = *(const s16x8*)(Qb + (size_t)(qw0 + mt * 16 + r16) * DK + kc * 32 + g * 8);

  STAGE_KV(0, KV_OF(0));

  f32x4 accd[2][4] = {};  // [mt][dsub]: O^T[d=dsub*16+4g+rr][q=qw0+mt*16+r16]
  float mrow[2] = {-INFINITY, -INFINITY};
  float lrow[2] = {0.0f, 0.0f};

  for (int t = 0; t < NT; ++t) {
    if (hf == 0 && t == tilesA) {
      // segA complete: final write for q-tile pid (both chains); reset for segB
#pragma unroll
      for (int mt = 0; mt < 2; ++mt) {
        float inv = 1.0f / lrow[mt];
        int srow = qw0 + mt * 16 + r16;
#pragma unroll
        for (int dsub = 0; dsub < 4; ++dsub) {
          int d0 = dsub * 16 + 4 * g;
          u16x4 o;
#pragma unroll
          for (int rr = 0; rr < 4; ++rr) o[rr] = f2bf(accd[mt][dsub][rr] * inv);
          *(u16x4*)&ctx[(((size_t)b * SS + srow) * HH + h) * DK + d0] = o;
        }
      }
      qw0 = q0B + wave * 32;
#pragma unroll
      for (int mt = 0; mt < 2; ++mt)
#pragma unroll
        for (int kc = 0; kc < 2; ++kc)
          aq[mt][kc] = *(const s16x8*)(Qb + (size_t)(qw0 + mt * 16 + r16) * DK + kc * 32 + g * 8);
#pragma unroll
      for (int mt = 0; mt < 2; ++mt) {
#pragma unroll
        for (int dsub = 0; dsub < 4; ++dsub) accd[mt][dsub] = (f32x4){0.f, 0.f, 0.f, 0.f};
        mrow[mt] = -INFINITY;
        lrow[mt] = 0.0f;
      }
    }

    int kv0 = KV_OF(t);

    __syncthreads();  // fence + drain + barrier (proven r10 sync)
    if (t + 1 < NT) STAGE_KV((t + 1) & 1, KV_OF(t + 1));

    const char* Kc = (const char*)Klds[t & 1];
    const char* Vc = (const char*)Vlds[t & 1];

    // ---- QK^T (swapped), both chains share bk fragments
    f32x4 sf[2][4] = {};
    __builtin_amdgcn_s_setprio(1);
#pragma unroll
    for (int kc = 0; kc < 2; ++kc) {
      s16x8 bk[4];
#pragma unroll
      for (int nt = 0; nt < 4; ++nt) {
        int row = rbase + 4 * (nt & 1) + 32 * (nt >> 1);
        int ch = (kc * 4 + g) ^ sk;
        bk[nt] = *(const s16x8*)(Kc + row * 128 + ch * 16);
      }
#pragma unroll
      for (int nt = 0; nt < 4; ++nt) {
        sf[0][nt] = mfma16(bk[nt], aq[0][kc], sf[0][nt]);
        sf[1][nt] = mfma16(bk[nt], aq[1][kc], sf[1][nt]);
      }
    }
    __builtin_amdgcn_s_setprio(0);

    // ---- prefetch V fragments (shared by both chains)
    s16x8 av[2][4];
#pragma unroll
    for (int c = 0; c < 2; ++c)
#pragma unroll
      for (int dsub = 0; dsub < 4; ++dsub) {
        int row = dsub * 16 + r16;
        int ch = (c * 4 + g) ^ (row & 7);
        av[c][dsub] = *(const s16x8*)(Vc + row * 128 + ch * 16);
      }

    bool domask = (kv0 + 63 > qw0);
    unsigned int pk[2][2][4];
#pragma unroll
    for (int mt = 0; mt < 2; ++mt) {
      // ---- mask (diagonal tiles only); finite sentinel
      if (domask) {
        int thr = qw0 + mt * 16 + r16 - kv0 - 8 * g;
#pragma unroll
        for (int nt = 0; nt < 4; ++nt) {
          int koff = 4 * (nt & 1) + 32 * (nt >> 1);
#pragma unroll
          for (int rr = 0; rr < 4; ++rr)
            if (koff + rr > thr) sf[mt][nt][rr] = NEGS;
        }
      }

      // ---- online softmax (log2 domain), tree reductions (depth 4)
      float m0v = fmaxf(fmaxf(sf[mt][0][0], sf[mt][0][1]), fmaxf(sf[mt][0][2], sf[mt][0][3]));
      float m1v = fmaxf(fmaxf(sf[mt][1][0], sf[mt][1][1]), fmaxf(sf[mt][1][2], sf[mt][1][3]));
      float m2v = fmaxf(fmaxf(sf[mt][2][0], sf[mt][2][1]), fmaxf(sf[mt][2][2], sf[mt][2][3]));
      float m3v = fmaxf(fmaxf(sf[mt][3][0], sf[mt][3][1]), fmaxf(sf[mt][3][2], sf[mt][3][3]));
      float tmax = fmaxf(fmaxf(m0v, m1v), fmaxf(m2v, m3v));
      tmax = fmaxf(tmax, __shfl_xor(tmax, 16));
      tmax = fmaxf(tmax, __shfl_xor(tmax, 32));

      if (!__all(tmax <= mrow[mt])) {  // exact defer
        float mn = fmaxf(mrow[mt], tmax);
        float fc = __builtin_amdgcn_exp2f(mrow[mt] - mn);
        lrow[mt] *= fc;
        mrow[mt] = mn;
#pragma unroll
        for (int dsub = 0; dsub < 4; ++dsub)
#pragma unroll
          for (int rr = 0; rr < 4; ++rr) accd[mt][dsub][rr] *= fc;
      }

      float pf[4][4];
#pragma unroll
      for (int nt = 0; nt < 4; ++nt)
#pragma unroll
        for (int rr = 0; rr < 4; ++rr)
          pf[nt][rr] = __builtin_amdgcn_exp2f(sf[mt][nt][rr] - mrow[mt]);
      float s0v = (pf[0][0] + pf[0][1]) + (pf[0][2] + pf[0][3]);
      float s1v = (pf[1][0] + pf[1][1]) + (pf[1][2] + pf[1][3]);
      float s2v = (pf[2][0] + pf[2][1]) + (pf[2][2] + pf[2][3]);
      float s3v = (pf[3][0] + pf[3][1]) + (pf[3][2] + pf[3][3]);
      float su = (s0v + s1v) + (s2v + s3v);
      su += __shfl_xor(su, 16);
      su += __shfl_xor(su, 32);
      lrow[mt] += su;

      // pack P^T fragments
#pragma unroll
      for (int c = 0; c < 2; ++c) {
        pk[mt][c][0] = cvtpk(pf[2 * c][0], pf[2 * c][1]);
        pk[mt][c][1] = cvtpk(pf[2 * c][2], pf[2 * c][3]);
        pk[mt][c][2] = cvtpk(pf[2 * c + 1][0], pf[2 * c + 1][1]);
        pk[mt][c][3] = cvtpk(pf[2 * c + 1][2], pf[2 * c + 1][3]);
      }
    }

    // ---- PV (swapped), av shared by both chains
    __builtin_amdgcn_s_setprio(1);
#pragma unroll
    for (int c = 0; c < 2; ++c) {
      s16x8 pb0 = __builtin_bit_cast(s16x8, *(u32x4*)pk[0][c]);
      s16x8 pb1 = __builtin_bit_cast(s16x8, *(u32x4*)pk[1][c]);
#pragma unroll
      for (int dsub = 0; dsub < 4; ++dsub) {
        accd[0][dsub] = mfma16(av[c][dsub], pb0, accd[0][dsub]);
        accd[1][dsub] = mfma16(av[c][dsub], pb1, accd[1][dsub]);
      }
    }
    __builtin_amdgcn_s_setprio(0);
  }

  // epilogue: write segB partial (slot = bh*8+pid, half hf), 128 rows/slot
#pragma unroll
  for (int mt = 0; mt < 2; ++mt) {
    size_t prow = ((size_t)bh * 8 + pid) * 128 + wave * 32 + mt * 16 + r16;
    float inv = 1.0f / lrow[mt];
    unsigned short* Op = Opart + ((size_t)hf * 32768 + prow) * 64;
#pragma unroll
    for (int dsub = 0; dsub < 4; ++dsub) {
      int d0 = dsub * 16 + 4 * g;
      u16x4 o;
#pragma unroll
      for (int rr = 0; rr < 4; ++rr) o[rr] = f2bf(accd[mt][dsub][rr] * inv);
      *(u16x4*)&Op[d0] = o;
    }
    if (g == 0) mlpart[(size_t)hf * 32768 + prow] = make_float2(mrow[mt], lrow[mt]);
  }
#undef STAGE_KV
#undef KV_OF
}

// ---------------- combine 2 partials per segB q-row ----------------
__global__ __launch_bounds__(256) void combine_kernel(const unsigned short* __restrict__ Opart,
                                                      const float2* __restrict__ mlpart,
                                                      unsigned short* __restrict__ ctx) {
  int idx = blockIdx.x * 256 + threadIdx.x;
  int row = idx >> 4;          // 32768 rows = 256 slots x 128 rows
  int d0 = (idx & 15) * 4;
  float2 ml0 = mlpart[row];
  float2 ml1 = mlpart[32768 + row];
  float m = fmaxf(ml0.x, ml1.x);
  float w0 = __builtin_amdgcn_exp2f(ml0.x - m) * ml0.y;
  float w1 = __builtin_amdgcn_exp2f(ml1.x - m) * ml1.y;
  float inv = 1.0f / (w0 + w1);
  w0 *= inv;
  w1 *= inv;
  u16x4 a = *(const u16x4*)(Opart + (size_t)row * 64 + d0);
  u16x4 bb4 = *(const u16x4*)(Opart + ((size_t)32768 + row) * 64 + d0);
  u16x4 o;
#pragma unroll
  for (int j = 0; j < 4; ++j) o[j] = f2bf(bf2f(a[j]) * w0 + bf2f(bb4[j]) * w1);
  int p = row >> 7, rin = row & 127;
  int bh = p >> 3, pid = p & 7;
  int srow = (15 - pid) * 128 + rin;
  int b = bh >> 4, h = bh & (HH - 1);
  *(u16x4*)&ctx[(((size_t)b * SS + srow) * HH + h) * DK + d0] = o;
}

extern "C" void kernel_launch(void* const* d_in, const int* in_sizes, int n_in,
                              void* d_out, int out_size, void* d_ws, size_t ws_size,
                              hipStream_t stream) {
  const float* q = (const float*)d_in[0];
  const float* k = (const float*)d_in[1];
  const float* v = (const float*)d_in[2];
  // d_in[3] = mask: exact causal tril, implemented in-kernel
  const float* Wq = (const float*)d_in[4];
  const float* bq = (const float*)d_in[5];
  const float* Wk = (const float*)d_in[6];
  const float* bk = (const float*)d_in[7];
  const float* Wv = (const float*)d_in[8];
  const float* bv = (const float*)d_in[9];
  const float* Wo = (const float*)d_in[10];
  const float* bo = (const float*)d_in[11];

  // Workspace layout (56 MB):
  //   [ 0, 8)  qb  -> reused as ctx
  //   [ 8,16)  kb  -> reused as Opart (2 x 4MB, dead after gemm_qkv)
  //   [16,24)  vb
  //   [24,32)  WT[4]; WqT region [24,26) -> reused as mlpart (512KB, dead after gemm_qkv)
  //   [32,40) Qh   [40,48) Kh   [48,56) VhT (written transposed by gemm_qkv)
  char* ws = (char*)d_ws;
  const size_t MB = 1ull << 20;
  unsigned short* qb = (unsigned short*)(ws + 0 * MB);
  unsigned short* kb = (unsigned short*)(ws + 8 * MB);
  unsigned short* vb = (unsigned short*)(ws + 16 * MB);
  unsigned short* WTbase = (unsigned short*)(ws + 24 * MB);
  unsigned short* WoT = (unsigned short*)(ws + 30 * MB);
  unsigned short* Qh = (unsigned short*)(ws + 32 * MB);
  unsigned short* Kh = (unsigned short*)(ws + 40 * MB);
  unsigned short* VhT = (unsigned short*)(ws + 48 * MB);
  unsigned short* ctx = (unsigned short*)(ws + 0 * MB);    // reuse qb
  unsigned short* Opart = (unsigned short*)(ws + 8 * MB);  // reuse kb (8MB)
  float2* mlpart = (float2*)(ws + 24 * MB);                // reuse WqT (512KB)

  // fused prologue: cvt3 (12288 blocks) + transpose_w4 (4096 blocks)
  prologue_kernel<<<16384, 256, 0, stream>>>(q, k, v, qb, kb, vb,
                                             Wq, Wk, Wv, Wo, WTbase);

  gemm_qkv_kernel<<<1536, 256, 0, stream>>>(qb, kb, vb, WTbase,
                                            bq, bk, bv, Qh, Kh, VhT);

  attn_kernel<<<512, 256, 0, stream>>>(Qh, Kh, VhT, ctx, Opart, mlpart);

  combine_kernel<<<2048, 256, 0, stream>>>(Opart, mlpart, ctx);

  gemm_out_kernel<<<512, 256, 0, stream>>>(ctx, WoT, bo, (float*)d_out);
}